// Round 10
// baseline (323.618 us; speedup 1.0000x reference)
//
#include <hip/hip_runtime.h>
#include <cstdint>
#include <cstddef>

typedef short bf16x8 __attribute__((ext_vector_type(8)));
typedef float f32x4 __attribute__((ext_vector_type(4)));

#define DM 1024
#define NHEADS 16
#define NGROUPS 4
#define DK 64
#define BATCH 2
#define SEQ 2048
#define MROWS 4096

#define QB_ELEMS   ((size_t)BATCH*NHEADS*SEQ*DK)   // 4M shorts
#define KB_ELEMS   ((size_t)BATCH*NGROUPS*SEQ*DK)  // 1M
#define VT_ELEMS   KB_ELEMS                        // 1M  ([b][g][d][col] permuted)
#define XC_ELEMS   ((size_t)MROWS*DM)              // 4M  (xbf, later reused as ctx)
#define WQKV_ELEMS ((size_t)1536*DM)
#define WO_ELEMS   ((size_t)DM*DM)

#define SCL_Q 0.180336880f    // (1/sqrt(64)) * log2(e), folded into Q

__device__ __forceinline__ ushort f2bf(float f) {          // RNE
    union { float f; uint32_t u; } a; a.f = f;
    uint32_t u = a.u;
    return (ushort)((u + 0x7FFFu + ((u >> 16) & 1u)) >> 16);
}

// async global->LDS, 16B/lane; LDS dest = wave-uniform base + lane*16
__device__ __forceinline__ void gll16(const void* g, void* l) {
    __builtin_amdgcn_global_load_lds((const __attribute__((address_space(1))) void*)g,
                                     (__attribute__((address_space(3))) void*)l, 16, 0, 0);
}

// 64x64 fp32->bf16 transpose tile through LDS (tl must be float[64][65])
__device__ __forceinline__ void transpose_tile(
        const float* __restrict__ src, int src_ld, ushort* __restrict__ dst,
        int r0, int c0, int tid, float (*tl)[65])
{
    const int rr = tid >> 4, cc = (tid & 15) * 4;
#pragma unroll
    for (int p = 0; p < 4; p++) {
        int r = rr + p * 16;
        float4 v = *(const float4*)(src + (size_t)(r0 + r) * src_ld + c0 + cc);
        tl[cc + 0][r] = v.x; tl[cc + 1][r] = v.y;
        tl[cc + 2][r] = v.z; tl[cc + 3][r] = v.w;
    }
    __syncthreads();
#pragma unroll
    for (int p = 0; p < 4; p++) {
        int c = rr + p * 16;
        ushort4 o;
        o.x = f2bf(tl[c][cc + 0]); o.y = f2bf(tl[c][cc + 1]);
        o.z = f2bf(tl[c][cc + 2]); o.w = f2bf(tl[c][cc + 3]);
        *(ushort4*)(dst + (size_t)(c0 + c) * 1024 + r0 + cc) = o;
    }
}

// ---------------------------------------------------------------------------
// Prep (641 blocks): W_Q/W_K/W_V transposes -> WqkvT, x fp32->bf16, bias.
// (W_O transpose rides inside the QKV GEMM launch.)  [R9-exact]
// ---------------------------------------------------------------------------
__global__ __launch_bounds__(256) void gqa_prep_kernel(
        const float* __restrict__ x,
        const float* __restrict__ WQ, const float* __restrict__ WK,
        const float* __restrict__ WV,
        const float* __restrict__ bQ, const float* __restrict__ bK,
        const float* __restrict__ bV,
        ushort* __restrict__ xbf, ushort* __restrict__ WqkvT,
        float* __restrict__ bcat)
{
    __shared__ float tl[64][65];
    const int bid = blockIdx.x, tid = threadIdx.x;
    if (bid < 256) {            // WQ [d][c] -> WqkvT rows c
        transpose_tile(WQ, 1024, WqkvT, (bid >> 4) * 64, (bid & 15) * 64, tid, tl);
    } else if (bid < 320) {     // WK[g] [d][k] -> rows 1024+g*64
        int t = bid - 256, g = t >> 4;
        transpose_tile(WK + (size_t)g * 1024 * 64, 64,
                       WqkvT + (size_t)(1024 + g * 64) * 1024,
                       (t & 15) * 64, 0, tid, tl);
    } else if (bid < 384) {     // WV[g] -> rows 1280+g*64
        int t = bid - 320, g = t >> 4;
        transpose_tile(WV + (size_t)g * 1024 * 64, 64,
                       WqkvT + (size_t)(1280 + g * 64) * 1024,
                       (t & 15) * 64, 0, tid, tl);
    } else if (bid < 640) {     // x convert
        int cid = bid - 384;
        const float* xs = x + (size_t)cid * 16384;
        ushort* xd = xbf + (size_t)cid * 16384;
#pragma unroll
        for (int p = 0; p < 16; p++) {
            float4 v = *(const float4*)(xs + p * 1024 + tid * 4);
            ushort4 o = { f2bf(v.x), f2bf(v.y), f2bf(v.z), f2bf(v.w) };
            *(ushort4*)(xd + p * 1024 + tid * 4) = o;
        }
    } else {
        for (int i = tid; i < 1536; i += 256) {
            float v = (i < 1024) ? bQ[i] : (i < 1280 ? bK[i - 1024] : bV[i - 1280]);
            bcat[i] = v;
        }
    }
}

// ---------------------------------------------------------------------------
// QKV GEMM (R9-exact): C[4096][1536] = A*B (+bias), BT[1536][1024].
// 128x128 tile, BK=64, 4 waves (2x2, wave 64x64, acc 4x4), gll16 dbuf,
// 1 barrier/iter, 64 KB LDS, launch_bounds(256,2).
// RIDERS: first 256 blocks transpose W_O.
// ---------------------------------------------------------------------------
template<int BN>
__global__ __launch_bounds__(256, 2) void gqa_qkv_kernel(
        const ushort* __restrict__ A, const ushort* __restrict__ BT,
        const float* __restrict__ bias,
        ushort* __restrict__ Qb, ushort* __restrict__ Kb, ushort* __restrict__ Vtg,
        const float* __restrict__ WO, ushort* __restrict__ WoT)
{
    __shared__ ushort smem[4][8192];     // As buf0/1, Bs buf0/1 (64 KB)
    const int tid = threadIdx.x;
    int i = blockIdx.x;

    if (i < 256) {   // W_O transpose rider
        float (*tl)[65] = (float(*)[65])&smem[0][0];
        transpose_tile(WO, 1024, WoT, (i >> 4) * 64, (i & 15) * 64, tid, tl);
        return;
    }
    i -= 256;

    const int xcd = i & 7, slot = i >> 3;
    const int bm = (slot / BN) * 8 + xcd;
    const int bn = slot % BN;
    const int wave = tid >> 6, lane = tid & 63;
    const int wm = (wave & 1) * 64, wn = (wave >> 1) * 64;
    const int lr = lane & 15, lq = lane >> 4;
    const int swz = lr & 7;

    const ushort* srcA[4]; const ushort* srcB[4]; int dstOff[4];
#pragma unroll
    for (int p = 0; p < 4; p++) {
        int slt = p * 256 + tid;
        int row = slt >> 3, cb = (slt & 7) ^ (row & 7);
        srcA[p] = A  + (size_t)(bm * 128 + row) * 1024 + cb * 8;
        srcB[p] = BT + (size_t)(bn * 128 + row) * 1024 + cb * 8;
        dstOff[p] = p * 2048 + wave * 512;
    }

    f32x4 acc[4][4];
#pragma unroll
    for (int ii = 0; ii < 4; ii++)
#pragma unroll
        for (int j = 0; j < 4; j++) acc[ii][j] = (f32x4){0.f, 0.f, 0.f, 0.f};

#pragma unroll
    for (int p = 0; p < 4; p++) {
        gll16(srcA[p], &smem[0][dstOff[p]]);
        gll16(srcB[p], &smem[2][dstOff[p]]);
    }

    for (int kt = 0; kt < 16; kt++) {
        __syncthreads();
        if (kt < 15) {
            int buf = (kt + 1) & 1, ko = (kt + 1) * 64;
#pragma unroll
            for (int p = 0; p < 4; p++) {
                gll16(srcA[p] + ko, &smem[buf][dstOff[p]]);
                gll16(srcB[p] + ko, &smem[2 + buf][dstOff[p]]);
            }
        }
        const ushort* as = smem[kt & 1];
        const ushort* bs = smem[2 + (kt & 1)];
        bf16x8 af[2][4], bfr[2][4];
#pragma unroll
        for (int kh = 0; kh < 2; kh++) {
#pragma unroll
            for (int ii = 0; ii < 4; ii++)
                af[kh][ii] = *(const bf16x8*)&as[(wm + ii * 16 + lr) * 64 + ((kh * 4 + lq) ^ swz) * 8];
#pragma unroll
            for (int j = 0; j < 4; j++)
                bfr[kh][j] = *(const bf16x8*)&bs[(wn + j * 16 + lr) * 64 + ((kh * 4 + lq) ^ swz) * 8];
        }
#pragma unroll
        for (int kh = 0; kh < 2; kh++)
#pragma unroll
            for (int ii = 0; ii < 4; ii++)
#pragma unroll
                for (int j = 0; j < 4; j++)
                    acc[ii][j] = __builtin_amdgcn_mfma_f32_16x16x32_bf16(af[kh][ii], bfr[kh][j], acc[ii][j], 0, 0, 0);
    }

#pragma unroll
    for (int ii = 0; ii < 4; ii++) {
        int mg = bm * 128 + wm + ii * 16 + lq * 4;
        int b = mg >> 11, s = mg & 2047;
#pragma unroll
        for (int j = 0; j < 4; j++) {
            int cg = bn * 128 + wn + j * 16 + lr;
            float bv = bias[cg];
            int d = cg & 63;
            if (cg < 1024) {
                int h = cg >> 6;
                ushort* dst = Qb + ((size_t)(b * NHEADS + h) * SEQ + s) * DK + d;
#pragma unroll
                for (int r = 0; r < 4; r++)
                    dst[r * DK] = f2bf((acc[ii][j][r] + bv) * SCL_Q);
            } else if (cg < 1280) {
                int g = (cg - 1024) >> 6;
                ushort* dst = Kb + ((size_t)(b * NGROUPS + g) * SEQ + s) * DK + d;
#pragma unroll
                for (int r = 0; r < 4; r++) dst[r * DK] = f2bf(acc[ii][j][r] + bv);
            } else {
                int g = (cg - 1280) >> 6;
                // permuted V^T column: 4-key group kg -> position (kg&3)*2+(kg>>2)
                int s4 = s >> 2, kg = s4 & 7;
                int col = ((s4 >> 3) << 5) + (((((kg & 3) << 1) | (kg >> 2))) << 2);
                ushort4 pk;
                pk.x = f2bf(acc[ii][j][0] + bv); pk.y = f2bf(acc[ii][j][1] + bv);
                pk.z = f2bf(acc[ii][j][2] + bv); pk.w = f2bf(acc[ii][j][3] + bv);
                *(ushort4*)(Vtg + ((size_t)(b * NGROUPS + g) * DK + d) * SEQ + col) = pk;
            }
        }
    }
}

// ---------------------------------------------------------------------------
// O-proj GEMM (R9-exact, NJ=2): C[4096][1024] = ctx*WoT + bO.
// Tile 128x64, BK=64, 4 waves (2x2, wave 64x32, acc 4x2), gll16 dbuf,
// 1 barrier/iter, 48 KB LDS -> 512 blocks at 2/CU, no atomics.
// ---------------------------------------------------------------------------
__global__ __launch_bounds__(256, 2) void gqa_oproj_kernel(
        const ushort* __restrict__ A, const ushort* __restrict__ BT,
        const float* __restrict__ bias, float* __restrict__ outF)
{
    constexpr int NJ = 2;
    constexpr int BNT = NJ * 32;                 // tile width 64
    __shared__ ushort smem[16384 + NJ * 4096];   // As dbuf + Bs dbuf (48 KB)
    ushort* As = smem;                           // 2 bufs x 8192 ushorts
    ushort* Bs = smem + 16384;                   // 2 bufs x NJ*2048 ushorts

    const int tid = threadIdx.x;
    const int i = blockIdx.x;
    const int xcd = i & 7, slot = i >> 3;        // slot 0..63
    const int bm = (slot >> 4) * 8 + xcd;        // 0..31
    const int bn = slot & 15;                    // 0..15
    const int wave = tid >> 6, lane = tid & 63;
    const int wm = (wave & 1) * 64, wn = (wave >> 1) * (NJ * 16);
    const int lr = lane & 15, lq = lane >> 4;
    const int swz = lr & 7;

    const ushort* srcA[4]; int dstOffA[4];
    const ushort* srcB[NJ]; int dstOffB[NJ];
#pragma unroll
    for (int p = 0; p < 4; p++) {
        int slt = p * 256 + tid;
        int row = slt >> 3, cb = (slt & 7) ^ (row & 7);
        srcA[p] = A + (size_t)(bm * 128 + row) * 1024 + cb * 8;
        dstOffA[p] = p * 2048 + wave * 512;
    }
#pragma unroll
    for (int p = 0; p < NJ; p++) {
        int slt = p * 256 + tid;
        int row = slt >> 3, cb = (slt & 7) ^ (row & 7);
        srcB[p] = BT + (size_t)(bn * BNT + row) * 1024 + cb * 8;
        dstOffB[p] = p * 2048 + wave * 512;
    }

    f32x4 acc[4][NJ];
#pragma unroll
    for (int ii = 0; ii < 4; ii++)
#pragma unroll
        for (int j = 0; j < NJ; j++) acc[ii][j] = (f32x4){0.f, 0.f, 0.f, 0.f};

#pragma unroll
    for (int p = 0; p < 4; p++) gll16(srcA[p], &As[dstOffA[p]]);
#pragma unroll
    for (int p = 0; p < NJ; p++) gll16(srcB[p], &Bs[dstOffB[p]]);

    for (int kt = 0; kt < 16; kt++) {
        __syncthreads();
        if (kt < 15) {
            int buf = (kt + 1) & 1, ko = (kt + 1) * 64;
#pragma unroll
            for (int p = 0; p < 4; p++)
                gll16(srcA[p] + ko, &As[buf * 8192 + dstOffA[p]]);
#pragma unroll
            for (int p = 0; p < NJ; p++)
                gll16(srcB[p] + ko, &Bs[buf * (NJ * 2048) + dstOffB[p]]);
        }
        const ushort* as = As + (kt & 1) * 8192;
        const ushort* bs = Bs + (kt & 1) * (NJ * 2048);
        bf16x8 af[2][4], bfr[2][NJ];
#pragma unroll
        for (int kh = 0; kh < 2; kh++) {
#pragma unroll
            for (int ii = 0; ii < 4; ii++)
                af[kh][ii] = *(const bf16x8*)&as[(wm + ii * 16 + lr) * 64 + ((kh * 4 + lq) ^ swz) * 8];
#pragma unroll
            for (int j = 0; j < NJ; j++)
                bfr[kh][j] = *(const bf16x8*)&bs[(wn + j * 16 + lr) * 64 + ((kh * 4 + lq) ^ swz) * 8];
        }
#pragma unroll
        for (int kh = 0; kh < 2; kh++)
#pragma unroll
            for (int ii = 0; ii < 4; ii++)
#pragma unroll
                for (int j = 0; j < NJ; j++)
                    acc[ii][j] = __builtin_amdgcn_mfma_f32_16x16x32_bf16(af[kh][ii], bfr[kh][j], acc[ii][j], 0, 0, 0);
    }

#pragma unroll
    for (int ii = 0; ii < 4; ii++) {
        int mg = bm * 128 + wm + ii * 16 + lq * 4;
#pragma unroll
        for (int j = 0; j < NJ; j++) {
            int cg = bn * BNT + wn + j * 16 + lr;
            float bv = bias[cg];
#pragma unroll
            for (int r = 0; r < 4; r++)
                outF[(size_t)(mg + r) * DM + cg] = acc[ii][j][r] + bv;
        }
    }
}

// ---------------------------------------------------------------------------
// Attention (R10): 512 blocks x 256 threads, XCD-local. Block = 128 q x
// full key sweep in 64-KEY tiles (32 iters). 4 waves 2x2 (wq 64q, wt 32t).
// LDS 32 KB dbuf (K 64x64, V^T 64x64) + 512B accX -> launch_bounds(256,4):
// 4 blocks/CU = 4 waves/SIMD from INDEPENDENT blocks -> block-phase drift
// lets one block's exp2 (trans pipe, ~20us of work) overlap another's MFMA
// (~15.5us). R9 counters: MfmaUtil 34 = VALUBusy 34 (not overlapped, 2
// blocks/CU). Total staging traffic unchanged vs R9 (same 512 blocks).
// Fragments = R6-validated 64-key-tile addressing; loops = R9's qs=4.
// ---------------------------------------------------------------------------
__global__ __launch_bounds__(256, 4) void gqa_attn_kernel(
        const ushort* __restrict__ Qb, const ushort* __restrict__ Kb,
        const ushort* __restrict__ Vtg, ushort* __restrict__ ctx)
{
    __shared__ ushort Ks[2][64 * 64];    // 16 KB
    __shared__ ushort Vs[2][64 * 64];    // 16 KB
    __shared__ float accXs[128];         // 512 B

    const int tid = threadIdx.x, wave = tid >> 6, lane = tid & 63;
    const int lr = lane & 15, lq = lane >> 4;
    const int swz = lr & 7;
    const int wq = wave & 1, wt = wave >> 1;       // wt in {0,1}
    const int i = blockIdx.x;
    const int bg = i & 7, s2 = i >> 3;
    const int qt = s2 & 15, h = s2 >> 4;
    const int b = bg >> 2, g = bg & 3, hg = g * 4 + h;

    const ushort* Qh = Qb  + (size_t)(b * NHEADS  + hg) * SEQ * DK;
    const ushort* Kg = Kb  + (size_t)(b * NGROUPS + g)  * SEQ * DK;
    const ushort* Vg = Vtg + (size_t)(b * NGROUPS + g)  * DK * SEQ;

    const int s0 = qt * 128 + wq * 64;
    const int tb = wt * 32;              // wave's 32-t stripe base within tile

    bf16x8 qf[4][2];
#pragma unroll
    for (int qs = 0; qs < 4; qs++)
#pragma unroll
        for (int kh = 0; kh < 2; kh++)
            qf[qs][kh] = *(const bf16x8*)(Qh + (size_t)(s0 + qs * 16 + lr) * DK + kh * 32 + lq * 8);

    // staging (256 thr, 2 slots each): K 64 rows x 8 chunks, XOR row&7;
    // V^T 64 rows(d) x 8 chunks (64 t), XOR row&7 (3-bit involution).
    const ushort* srcK[2]; const ushort* srcV[2]; int dstOff[2];
#pragma unroll
    for (int p = 0; p < 2; p++) {
        int slt = p * 256 + tid;
        int krow = slt >> 3, kcb = (slt & 7) ^ (krow & 7);
        srcK[p] = Kg + (size_t)krow * DK + kcb * 8;
        int vrow = slt >> 3, vc = slt & 7;
        int vcb = (vc ^ vrow) & 7;
        srcV[p] = Vg + (size_t)vrow * SEQ + vcb * 8;
        dstOff[p] = (p * 256 + wave * 64) * 8;   // ushort offset; lane*16B added by HW
    }

    f32x4 of[4][4];
#pragma unroll
    for (int qs = 0; qs < 4; qs++)
#pragma unroll
        for (int j = 0; j < 4; j++) of[qs][j] = (f32x4){0.f, 0.f, 0.f, 0.f};
    f32x4 accL[4];
#pragma unroll
    for (int qs = 0; qs < 4; qs++) accL[qs] = (f32x4){0.f, 0.f, 0.f, 0.f};

    bf16x8 ones;
#pragma unroll
    for (int k = 0; k < 8; k++) ones[k] = (short)0x3F80;

#pragma unroll
    for (int p = 0; p < 2; p++) {
        gll16(srcK[p], &Ks[0][dstOff[p]]);
        gll16(srcV[p], &Vs[0][dstOff[p]]);
    }

    for (int it = 0; it < 32; it++) {
        __syncthreads();
        if (it < 31) {
            int buf = (it + 1) & 1, t0 = (it + 1) * 64;
#pragma unroll
            for (int p = 0; p < 2; p++) {
                gll16(srcK[p] + (size_t)t0 * DK, &Ks[buf][dstOff[p]]);
                gll16(srcV[p] + t0, &Vs[buf][dstOff[p]]);
            }
        }
        const ushort* ks = Ks[it & 1];
        const ushort* vs = Vs[it & 1];

        bf16x8 kf[2][2];
#pragma unroll
        for (int nt = 0; nt < 2; nt++)
#pragma unroll
            for (int kh = 0; kh < 2; kh++)
                kf[nt][kh] = *(const bf16x8*)&ks[(tb + nt * 16 + lr) * 64 + ((kh * 4 + lq) ^ swz) * 8];

        bf16x8 vf[4];
        {
            int gch = wt * 4 + lq;                 // wave's t-chunk (8 t each)
            int vc2 = (gch ^ swz) & 7;             // undo write-side XOR
#pragma unroll
            for (int j = 0; j < 4; j++)
                vf[j] = *(const bf16x8*)&vs[(j * 16 + lr) * 64 + vc2 * 8];
        }

        // S^T[t][q] over the wave's 32-t stripe (Q pre-scaled -> log2 domain)
        f32x4 sc[4][2];
        __builtin_amdgcn_s_setprio(1);
#pragma unroll
        for (int qs = 0; qs < 4; qs++)
#pragma unroll
            for (int nt = 0; nt < 2; nt++) {
                f32x4 s = (f32x4){0.f, 0.f, 0.f, 0.f};
                s = __builtin_amdgcn_mfma_f32_16x16x32_bf16(kf[nt][0], qf[qs][0], s, 0, 0, 0);
                s = __builtin_amdgcn_mfma_f32_16x16x32_bf16(kf[nt][1], qf[qs][1], s, 0, 0, 0);
                sc[qs][nt] = s;
            }
        __builtin_amdgcn_s_setprio(0);

        // exp2 -> truncate-pack into one K=32 B-frag per qs (trans/VALU phase)
        union PF { bf16x8 v; uint32_t w[4]; };
        PF pf[4];
#pragma unroll
        for (int qs = 0; qs < 4; qs++)
#pragma unroll
            for (int nt = 0; nt < 2; nt++) {
                union { float f; uint32_t u; } e0, e1, e2, e3;
                e0.f = __builtin_amdgcn_exp2f(sc[qs][nt][0]);
                e1.f = __builtin_amdgcn_exp2f(sc[qs][nt][1]);
                e2.f = __builtin_amdgcn_exp2f(sc[qs][nt][2]);
                e3.f = __builtin_amdgcn_exp2f(sc[qs][nt][3]);
                pf[qs].w[nt * 2 + 0] = __builtin_amdgcn_perm(e1.u, e0.u, 0x07060302u);
                pf[qs].w[nt * 2 + 1] = __builtin_amdgcn_perm(e3.u, e2.u, 0x07060302u);
            }

        // sums + O^T[d][q] += V^T(stripe) . P  (MFMA cluster 2)
        __builtin_amdgcn_s_setprio(1);
#pragma unroll
        for (int qs = 0; qs < 4; qs++)
            accL[qs] = __builtin_amdgcn_mfma_f32_16x16x32_bf16(ones, pf[qs].v, accL[qs], 0, 0, 0);
#pragma unroll
        for (int qs = 0; qs < 4; qs++)
#pragma unroll
            for (int j = 0; j < 4; j++)
                of[qs][j] = __builtin_amdgcn_mfma_f32_16x16x32_bf16(vf[j], pf[qs].v, of[qs][j], 0, 0, 0);
        __builtin_amdgcn_s_setprio(0);
    }

    // ---- combine t-halves (wt=1 -> LDS overlay -> wt=0 adds) ----
    // wq=0 partials in Ks (16 KB), wq=1 partials in Vs (16 KB).
    __syncthreads();                       // all staging reads done; overlay safe
    float* cw = (wq == 0) ? (float*)&Ks[0][0] : (float*)&Vs[0][0];
    if (wt == 1) {
#pragma unroll
        for (int qs = 0; qs < 4; qs++)
#pragma unroll
            for (int j = 0; j < 4; j++)
                *(f32x4*)&cw[(qs * 4 + j) * 256 + lane * 4] = of[qs][j];
        if (lq == 0) {
#pragma unroll
            for (int qs = 0; qs < 4; qs++) accXs[(wq * 4 + qs) * 16 + lr] = accL[qs][0];
        }
    }
    __syncthreads();
    if (wt == 0) {
        float inv[4];
#pragma unroll
        for (int qs = 0; qs < 4; qs++)
            inv[qs] = 1.0f / (accL[qs][0] + accXs[(wq * 4 + qs) * 16 + lr]);
        ushort* cbp = ctx + (size_t)b * SEQ * DM;
#pragma unroll
        for (int qs = 0; qs < 4; qs++) {
            int s = s0 + qs * 16 + lr;
#pragma unroll
            for (int j = 0; j < 4; j++) {
                f32x4 o2 = of[qs][j] + *(const f32x4*)&cw[(qs * 4 + j) * 256 + lane * 4];
                ushort4 o;
                o.x = f2bf(o2[0] * inv[qs]);
                o.y = f2bf(o2[1] * inv[qs]);
                o.z = f2bf(o2[2] * inv[qs]);
                o.w = f2bf(o2[3] * inv[qs]);
                *(ushort4*)(cbp + (size_t)s * DM + hg * 64 + j * 16 + lq * 4) = o;
            }
        }
    }
}

// ---------------------------------------------------------------------------
extern "C" void kernel_launch(void* const* d_in, const int* in_sizes, int n_in,
                              void* d_out, int out_size, void* d_ws, size_t ws_size,
                              hipStream_t stream) {
    const float* x  = (const float*)d_in[0];
    const float* WQ = (const float*)d_in[1];
    const float* bQ = (const float*)d_in[2];
    const float* WK = (const float*)d_in[3];
    const float* bK = (const float*)d_in[4];
    const float* WV = (const float*)d_in[5];
    const float* bV = (const float*)d_in[6];
    const float* WO = (const float*)d_in[7];
    const float* bO = (const float*)d_in[8];

    ushort* Qb    = (ushort*)d_ws;
    ushort* Kb    = Qb + QB_ELEMS;
    ushort* Vtg   = Kb + KB_ELEMS;
    ushort* xc    = Vtg + VT_ELEMS;       // xbf (QKV input), later reused as ctx
    ushort* WqkvT = xc + XC_ELEMS;
    ushort* WoT   = WqkvT + WQKV_ELEMS;
    float*  bcat  = (float*)(WoT + WO_ELEMS);

    gqa_prep_kernel<<<641, 256, 0, stream>>>(x, WQ, WK, WV, bQ, bK, bV,
                                             xc, WqkvT, bcat);
    // QKV: 256 riders + 32x12 = 640 blocks (128x128 tiles, N=1536)
    gqa_qkv_kernel<12><<<640, 256, 0, stream>>>(
        xc, WqkvT, bcat, Qb, Kb, Vtg, WO, WoT);
    // attention: 512 blocks x 4 waves, 32 KB LDS -> 4 blocks/CU
    gqa_attn_kernel<<<512, 256, 0, stream>>>(Qb, Kb, Vtg, xc);
    // O-proj: 32x16 = 512 tiles of 128x64 (2 blocks/CU, no atomics)
    gqa_oproj_kernel<<<512, 256, 0, stream>>>(xc, WoT, bO, (float*)d_out);
}

// Round 11
// 158.764 us; speedup vs baseline: 2.0384x; 2.0384x over previous
//
#include <hip/hip_runtime.h>
#include <cstdint>
#include <cstddef>

typedef short bf16x8 __attribute__((ext_vector_type(8)));
typedef float f32x4 __attribute__((ext_vector_type(4)));

#define DM 1024
#define NHEADS 16
#define NGROUPS 4
#define DK 64
#define BATCH 2
#define SEQ 2048
#define MROWS 4096

#define QB_ELEMS   ((size_t)BATCH*NHEADS*SEQ*DK)   // 4M shorts
#define KB_ELEMS   ((size_t)BATCH*NGROUPS*SEQ*DK)  // 1M
#define VT_ELEMS   KB_ELEMS                        // 1M  ([b][g][d][col] permuted)
#define XC_ELEMS   ((size_t)MROWS*DM)              // 4M  (xbf, later reused as ctx)
#define WQKV_ELEMS ((size_t)1536*DM)
#define WO_ELEMS   ((size_t)DM*DM)

#define SCL_Q 0.180336880f    // (1/sqrt(64)) * log2(e), folded into Q

__device__ __forceinline__ ushort f2bf(float f) {          // RNE
    union { float f; uint32_t u; } a; a.f = f;
    uint32_t u = a.u;
    return (ushort)((u + 0x7FFFu + ((u >> 16) & 1u)) >> 16);
}

// async global->LDS, 16B/lane; LDS dest = wave-uniform base + lane*16
__device__ __forceinline__ void gll16(const void* g, void* l) {
    __builtin_amdgcn_global_load_lds((const __attribute__((address_space(1))) void*)g,
                                     (__attribute__((address_space(3))) void*)l, 16, 0, 0);
}

// 64x64 fp32->bf16 transpose tile through LDS (tl must be float[64][65])
__device__ __forceinline__ void transpose_tile(
        const float* __restrict__ src, int src_ld, ushort* __restrict__ dst,
        int r0, int c0, int tid, float (*tl)[65])
{
    const int rr = tid >> 4, cc = (tid & 15) * 4;
#pragma unroll
    for (int p = 0; p < 4; p++) {
        int r = rr + p * 16;
        float4 v = *(const float4*)(src + (size_t)(r0 + r) * src_ld + c0 + cc);
        tl[cc + 0][r] = v.x; tl[cc + 1][r] = v.y;
        tl[cc + 2][r] = v.z; tl[cc + 3][r] = v.w;
    }
    __syncthreads();
#pragma unroll
    for (int p = 0; p < 4; p++) {
        int c = rr + p * 16;
        ushort4 o;
        o.x = f2bf(tl[c][cc + 0]); o.y = f2bf(tl[c][cc + 1]);
        o.z = f2bf(tl[c][cc + 2]); o.w = f2bf(tl[c][cc + 3]);
        *(ushort4*)(dst + (size_t)(c0 + c) * 1024 + r0 + cc) = o;
    }
}

// ---------------------------------------------------------------------------
// Prep (641 blocks): W_Q/W_K/W_V transposes -> WqkvT, x fp32->bf16, bias.
// (W_O transpose rides inside the QKV GEMM launch.)  [R9-exact]
// ---------------------------------------------------------------------------
__global__ __launch_bounds__(256) void gqa_prep_kernel(
        const float* __restrict__ x,
        const float* __restrict__ WQ, const float* __restrict__ WK,
        const float* __restrict__ WV,
        const float* __restrict__ bQ, const float* __restrict__ bK,
        const float* __restrict__ bV,
        ushort* __restrict__ xbf, ushort* __restrict__ WqkvT,
        float* __restrict__ bcat)
{
    __shared__ float tl[64][65];
    const int bid = blockIdx.x, tid = threadIdx.x;
    if (bid < 256) {            // WQ [d][c] -> WqkvT rows c
        transpose_tile(WQ, 1024, WqkvT, (bid >> 4) * 64, (bid & 15) * 64, tid, tl);
    } else if (bid < 320) {     // WK[g] [d][k] -> rows 1024+g*64
        int t = bid - 256, g = t >> 4;
        transpose_tile(WK + (size_t)g * 1024 * 64, 64,
                       WqkvT + (size_t)(1024 + g * 64) * 1024,
                       (t & 15) * 64, 0, tid, tl);
    } else if (bid < 384) {     // WV[g] -> rows 1280+g*64
        int t = bid - 320, g = t >> 4;
        transpose_tile(WV + (size_t)g * 1024 * 64, 64,
                       WqkvT + (size_t)(1280 + g * 64) * 1024,
                       (t & 15) * 64, 0, tid, tl);
    } else if (bid < 640) {     // x convert
        int cid = bid - 384;
        const float* xs = x + (size_t)cid * 16384;
        ushort* xd = xbf + (size_t)cid * 16384;
#pragma unroll
        for (int p = 0; p < 16; p++) {
            float4 v = *(const float4*)(xs + p * 1024 + tid * 4);
            ushort4 o = { f2bf(v.x), f2bf(v.y), f2bf(v.z), f2bf(v.w) };
            *(ushort4*)(xd + p * 1024 + tid * 4) = o;
        }
    } else {
        for (int i = tid; i < 1536; i += 256) {
            float v = (i < 1024) ? bQ[i] : (i < 1280 ? bK[i - 1024] : bV[i - 1280]);
            bcat[i] = v;
        }
    }
}

// ---------------------------------------------------------------------------
// QKV GEMM (R9-exact): C[4096][1536] = A*B (+bias), BT[1536][1024].
// 128x128 tile, BK=64, 4 waves (2x2, wave 64x64, acc 4x4), gll16 dbuf,
// 1 barrier/iter, 64 KB LDS, launch_bounds(256,2).
// RIDERS: first 256 blocks transpose W_O.
// ---------------------------------------------------------------------------
template<int BN>
__global__ __launch_bounds__(256, 2) void gqa_qkv_kernel(
        const ushort* __restrict__ A, const ushort* __restrict__ BT,
        const float* __restrict__ bias,
        ushort* __restrict__ Qb, ushort* __restrict__ Kb, ushort* __restrict__ Vtg,
        const float* __restrict__ WO, ushort* __restrict__ WoT)
{
    __shared__ ushort smem[4][8192];     // As buf0/1, Bs buf0/1 (64 KB)
    const int tid = threadIdx.x;
    int i = blockIdx.x;

    if (i < 256) {   // W_O transpose rider
        float (*tl)[65] = (float(*)[65])&smem[0][0];
        transpose_tile(WO, 1024, WoT, (i >> 4) * 64, (i & 15) * 64, tid, tl);
        return;
    }
    i -= 256;

    const int xcd = i & 7, slot = i >> 3;
    const int bm = (slot / BN) * 8 + xcd;
    const int bn = slot % BN;
    const int wave = tid >> 6, lane = tid & 63;
    const int wm = (wave & 1) * 64, wn = (wave >> 1) * 64;
    const int lr = lane & 15, lq = lane >> 4;
    const int swz = lr & 7;

    const ushort* srcA[4]; const ushort* srcB[4]; int dstOff[4];
#pragma unroll
    for (int p = 0; p < 4; p++) {
        int slt = p * 256 + tid;
        int row = slt >> 3, cb = (slt & 7) ^ (row & 7);
        srcA[p] = A  + (size_t)(bm * 128 + row) * 1024 + cb * 8;
        srcB[p] = BT + (size_t)(bn * 128 + row) * 1024 + cb * 8;
        dstOff[p] = p * 2048 + wave * 512;
    }

    f32x4 acc[4][4];
#pragma unroll
    for (int ii = 0; ii < 4; ii++)
#pragma unroll
        for (int j = 0; j < 4; j++) acc[ii][j] = (f32x4){0.f, 0.f, 0.f, 0.f};

#pragma unroll
    for (int p = 0; p < 4; p++) {
        gll16(srcA[p], &smem[0][dstOff[p]]);
        gll16(srcB[p], &smem[2][dstOff[p]]);
    }

    for (int kt = 0; kt < 16; kt++) {
        __syncthreads();
        if (kt < 15) {
            int buf = (kt + 1) & 1, ko = (kt + 1) * 64;
#pragma unroll
            for (int p = 0; p < 4; p++) {
                gll16(srcA[p] + ko, &smem[buf][dstOff[p]]);
                gll16(srcB[p] + ko, &smem[2 + buf][dstOff[p]]);
            }
        }
        const ushort* as = smem[kt & 1];
        const ushort* bs = smem[2 + (kt & 1)];
        bf16x8 af[2][4], bfr[2][4];
#pragma unroll
        for (int kh = 0; kh < 2; kh++) {
#pragma unroll
            for (int ii = 0; ii < 4; ii++)
                af[kh][ii] = *(const bf16x8*)&as[(wm + ii * 16 + lr) * 64 + ((kh * 4 + lq) ^ swz) * 8];
#pragma unroll
            for (int j = 0; j < 4; j++)
                bfr[kh][j] = *(const bf16x8*)&bs[(wn + j * 16 + lr) * 64 + ((kh * 4 + lq) ^ swz) * 8];
        }
#pragma unroll
        for (int kh = 0; kh < 2; kh++)
#pragma unroll
            for (int ii = 0; ii < 4; ii++)
#pragma unroll
                for (int j = 0; j < 4; j++)
                    acc[ii][j] = __builtin_amdgcn_mfma_f32_16x16x32_bf16(af[kh][ii], bfr[kh][j], acc[ii][j], 0, 0, 0);
    }

#pragma unroll
    for (int ii = 0; ii < 4; ii++) {
        int mg = bm * 128 + wm + ii * 16 + lq * 4;
        int b = mg >> 11, s = mg & 2047;
#pragma unroll
        for (int j = 0; j < 4; j++) {
            int cg = bn * 128 + wn + j * 16 + lr;
            float bv = bias[cg];
            int d = cg & 63;
            if (cg < 1024) {
                int h = cg >> 6;
                ushort* dst = Qb + ((size_t)(b * NHEADS + h) * SEQ + s) * DK + d;
#pragma unroll
                for (int r = 0; r < 4; r++)
                    dst[r * DK] = f2bf((acc[ii][j][r] + bv) * SCL_Q);
            } else if (cg < 1280) {
                int g = (cg - 1024) >> 6;
                ushort* dst = Kb + ((size_t)(b * NGROUPS + g) * SEQ + s) * DK + d;
#pragma unroll
                for (int r = 0; r < 4; r++) dst[r * DK] = f2bf(acc[ii][j][r] + bv);
            } else {
                int g = (cg - 1280) >> 6;
                // permuted V^T column: 4-key group kg -> position (kg&3)*2+(kg>>2)
                int s4 = s >> 2, kg = s4 & 7;
                int col = ((s4 >> 3) << 5) + (((((kg & 3) << 1) | (kg >> 2))) << 2);
                ushort4 pk;
                pk.x = f2bf(acc[ii][j][0] + bv); pk.y = f2bf(acc[ii][j][1] + bv);
                pk.z = f2bf(acc[ii][j][2] + bv); pk.w = f2bf(acc[ii][j][3] + bv);
                *(ushort4*)(Vtg + ((size_t)(b * NGROUPS + g) * DK + d) * SEQ + col) = pk;
            }
        }
    }
}

// ---------------------------------------------------------------------------
// O-proj GEMM (R9-exact, NJ=2): C[4096][1024] = ctx*WoT + bO.
// Tile 128x64, BK=64, 4 waves (2x2, wave 64x32, acc 4x2), gll16 dbuf,
// 1 barrier/iter, 48 KB LDS -> 512 blocks at 2/CU, no atomics.
// ---------------------------------------------------------------------------
__global__ __launch_bounds__(256, 2) void gqa_oproj_kernel(
        const ushort* __restrict__ A, const ushort* __restrict__ BT,
        const float* __restrict__ bias, float* __restrict__ outF)
{
    constexpr int NJ = 2;
    constexpr int BNT = NJ * 32;                 // tile width 64
    __shared__ ushort smem[16384 + NJ * 4096];   // As dbuf + Bs dbuf (48 KB)
    ushort* As = smem;                           // 2 bufs x 8192 ushorts
    ushort* Bs = smem + 16384;                   // 2 bufs x NJ*2048 ushorts

    const int tid = threadIdx.x;
    const int i = blockIdx.x;
    const int xcd = i & 7, slot = i >> 3;        // slot 0..63
    const int bm = (slot >> 4) * 8 + xcd;        // 0..31
    const int bn = slot & 15;                    // 0..15
    const int wave = tid >> 6, lane = tid & 63;
    const int wm = (wave & 1) * 64, wn = (wave >> 1) * (NJ * 16);
    const int lr = lane & 15, lq = lane >> 4;
    const int swz = lr & 7;

    const ushort* srcA[4]; int dstOffA[4];
    const ushort* srcB[NJ]; int dstOffB[NJ];
#pragma unroll
    for (int p = 0; p < 4; p++) {
        int slt = p * 256 + tid;
        int row = slt >> 3, cb = (slt & 7) ^ (row & 7);
        srcA[p] = A + (size_t)(bm * 128 + row) * 1024 + cb * 8;
        dstOffA[p] = p * 2048 + wave * 512;
    }
#pragma unroll
    for (int p = 0; p < NJ; p++) {
        int slt = p * 256 + tid;
        int row = slt >> 3, cb = (slt & 7) ^ (row & 7);
        srcB[p] = BT + (size_t)(bn * BNT + row) * 1024 + cb * 8;
        dstOffB[p] = p * 2048 + wave * 512;
    }

    f32x4 acc[4][NJ];
#pragma unroll
    for (int ii = 0; ii < 4; ii++)
#pragma unroll
        for (int j = 0; j < NJ; j++) acc[ii][j] = (f32x4){0.f, 0.f, 0.f, 0.f};

#pragma unroll
    for (int p = 0; p < 4; p++) gll16(srcA[p], &As[dstOffA[p]]);
#pragma unroll
    for (int p = 0; p < NJ; p++) gll16(srcB[p], &Bs[dstOffB[p]]);

    for (int kt = 0; kt < 16; kt++) {
        __syncthreads();
        if (kt < 15) {
            int buf = (kt + 1) & 1, ko = (kt + 1) * 64;
#pragma unroll
            for (int p = 0; p < 4; p++)
                gll16(srcA[p] + ko, &As[buf * 8192 + dstOffA[p]]);
#pragma unroll
            for (int p = 0; p < NJ; p++)
                gll16(srcB[p] + ko, &Bs[buf * (NJ * 2048) + dstOffB[p]]);
        }
        const ushort* as = As + (kt & 1) * 8192;
        const ushort* bs = Bs + (kt & 1) * (NJ * 2048);
        bf16x8 af[2][4], bfr[2][NJ];
#pragma unroll
        for (int kh = 0; kh < 2; kh++) {
#pragma unroll
            for (int ii = 0; ii < 4; ii++)
                af[kh][ii] = *(const bf16x8*)&as[(wm + ii * 16 + lr) * 64 + ((kh * 4 + lq) ^ swz) * 8];
#pragma unroll
            for (int j = 0; j < NJ; j++)
                bfr[kh][j] = *(const bf16x8*)&bs[(wn + j * 16 + lr) * 64 + ((kh * 4 + lq) ^ swz) * 8];
        }
#pragma unroll
        for (int kh = 0; kh < 2; kh++)
#pragma unroll
            for (int ii = 0; ii < 4; ii++)
#pragma unroll
                for (int j = 0; j < NJ; j++)
                    acc[ii][j] = __builtin_amdgcn_mfma_f32_16x16x32_bf16(af[kh][ii], bfr[kh][j], acc[ii][j], 0, 0, 0);
    }

#pragma unroll
    for (int ii = 0; ii < 4; ii++) {
        int mg = bm * 128 + wm + ii * 16 + lq * 4;
#pragma unroll
        for (int j = 0; j < NJ; j++) {
            int cg = bn * BNT + wn + j * 16 + lr;
            float bv = bias[cg];
#pragma unroll
            for (int r = 0; r < 4; r++)
                outF[(size_t)(mg + r) * DM + cg] = acc[ii][j][r] + bv;
        }
    }
}

// ---------------------------------------------------------------------------
// Attention (R11 = R10 body, launch_bounds(256,2)): 512 blocks x 256 thr.
// Block = 128 q x full key sweep in 64-key tiles (32 iters). 4 waves 2x2
// (wq 64q, wt 32t). LDS 32 KB dbuf + 512B accX. R10's (256,4) bound made
// the allocator squeeze to 64 VGPR and spill (FETCH 207MB/WRITE 422MB) --
// twice-reproduced rule: min-waves=4 => 64-VGPR target. With (256,2) the
// body compiles ~100-116 VGPR spill-free (like R9) and HW occupancy is
// resource-limited: LDS 33.3KB -> 4 blocks/CU, VGPR <=128 -> 4 waves/SIMD.
// Cross-block phase drift then overlaps one block's exp2 (trans pipe) with
// another's MFMA. Numerics of this body already HW-validated (R10 passed).
// ---------------------------------------------------------------------------
__global__ __launch_bounds__(256, 2) void gqa_attn_kernel(
        const ushort* __restrict__ Qb, const ushort* __restrict__ Kb,
        const ushort* __restrict__ Vtg, ushort* __restrict__ ctx)
{
    __shared__ ushort Ks[2][64 * 64];    // 16 KB
    __shared__ ushort Vs[2][64 * 64];    // 16 KB
    __shared__ float accXs[128];         // 512 B

    const int tid = threadIdx.x, wave = tid >> 6, lane = tid & 63;
    const int lr = lane & 15, lq = lane >> 4;
    const int swz = lr & 7;
    const int wq = wave & 1, wt = wave >> 1;       // wt in {0,1}
    const int i = blockIdx.x;
    const int bg = i & 7, s2 = i >> 3;
    const int qt = s2 & 15, h = s2 >> 4;
    const int b = bg >> 2, g = bg & 3, hg = g * 4 + h;

    const ushort* Qh = Qb  + (size_t)(b * NHEADS  + hg) * SEQ * DK;
    const ushort* Kg = Kb  + (size_t)(b * NGROUPS + g)  * SEQ * DK;
    const ushort* Vg = Vtg + (size_t)(b * NGROUPS + g)  * DK * SEQ;

    const int s0 = qt * 128 + wq * 64;
    const int tb = wt * 32;              // wave's 32-t stripe base within tile

    bf16x8 qf[4][2];
#pragma unroll
    for (int qs = 0; qs < 4; qs++)
#pragma unroll
        for (int kh = 0; kh < 2; kh++)
            qf[qs][kh] = *(const bf16x8*)(Qh + (size_t)(s0 + qs * 16 + lr) * DK + kh * 32 + lq * 8);

    // staging (256 thr, 2 slots each): K 64 rows x 8 chunks, XOR row&7;
    // V^T 64 rows(d) x 8 chunks (64 t), XOR row&7 (3-bit involution).
    const ushort* srcK[2]; const ushort* srcV[2]; int dstOff[2];
#pragma unroll
    for (int p = 0; p < 2; p++) {
        int slt = p * 256 + tid;
        int krow = slt >> 3, kcb = (slt & 7) ^ (krow & 7);
        srcK[p] = Kg + (size_t)krow * DK + kcb * 8;
        int vrow = slt >> 3, vc = slt & 7;
        int vcb = (vc ^ vrow) & 7;
        srcV[p] = Vg + (size_t)vrow * SEQ + vcb * 8;
        dstOff[p] = (p * 256 + wave * 64) * 8;   // ushort offset; lane*16B added by HW
    }

    f32x4 of[4][4];
#pragma unroll
    for (int qs = 0; qs < 4; qs++)
#pragma unroll
        for (int j = 0; j < 4; j++) of[qs][j] = (f32x4){0.f, 0.f, 0.f, 0.f};
    f32x4 accL[4];
#pragma unroll
    for (int qs = 0; qs < 4; qs++) accL[qs] = (f32x4){0.f, 0.f, 0.f, 0.f};

    bf16x8 ones;
#pragma unroll
    for (int k = 0; k < 8; k++) ones[k] = (short)0x3F80;

#pragma unroll
    for (int p = 0; p < 2; p++) {
        gll16(srcK[p], &Ks[0][dstOff[p]]);
        gll16(srcV[p], &Vs[0][dstOff[p]]);
    }

    for (int it = 0; it < 32; it++) {
        __syncthreads();
        if (it < 31) {
            int buf = (it + 1) & 1, t0 = (it + 1) * 64;
#pragma unroll
            for (int p = 0; p < 2; p++) {
                gll16(srcK[p] + (size_t)t0 * DK, &Ks[buf][dstOff[p]]);
                gll16(srcV[p] + t0, &Vs[buf][dstOff[p]]);
            }
        }
        const ushort* ks = Ks[it & 1];
        const ushort* vs = Vs[it & 1];

        bf16x8 kf[2][2];
#pragma unroll
        for (int nt = 0; nt < 2; nt++)
#pragma unroll
            for (int kh = 0; kh < 2; kh++)
                kf[nt][kh] = *(const bf16x8*)&ks[(tb + nt * 16 + lr) * 64 + ((kh * 4 + lq) ^ swz) * 8];

        bf16x8 vf[4];
        {
            int gch = wt * 4 + lq;                 // wave's t-chunk (8 t each)
            int vc2 = (gch ^ swz) & 7;             // undo write-side XOR
#pragma unroll
            for (int j = 0; j < 4; j++)
                vf[j] = *(const bf16x8*)&vs[(j * 16 + lr) * 64 + vc2 * 8];
        }

        // S^T[t][q] over the wave's 32-t stripe (Q pre-scaled -> log2 domain)
        f32x4 sc[4][2];
        __builtin_amdgcn_s_setprio(1);
#pragma unroll
        for (int qs = 0; qs < 4; qs++)
#pragma unroll
            for (int nt = 0; nt < 2; nt++) {
                f32x4 s = (f32x4){0.f, 0.f, 0.f, 0.f};
                s = __builtin_amdgcn_mfma_f32_16x16x32_bf16(kf[nt][0], qf[qs][0], s, 0, 0, 0);
                s = __builtin_amdgcn_mfma_f32_16x16x32_bf16(kf[nt][1], qf[qs][1], s, 0, 0, 0);
                sc[qs][nt] = s;
            }
        __builtin_amdgcn_s_setprio(0);

        // exp2 -> truncate-pack into one K=32 B-frag per qs (trans/VALU phase)
        union PF { bf16x8 v; uint32_t w[4]; };
        PF pf[4];
#pragma unroll
        for (int qs = 0; qs < 4; qs++)
#pragma unroll
            for (int nt = 0; nt < 2; nt++) {
                union { float f; uint32_t u; } e0, e1, e2, e3;
                e0.f = __builtin_amdgcn_exp2f(sc[qs][nt][0]);
                e1.f = __builtin_amdgcn_exp2f(sc[qs][nt][1]);
                e2.f = __builtin_amdgcn_exp2f(sc[qs][nt][2]);
                e3.f = __builtin_amdgcn_exp2f(sc[qs][nt][3]);
                pf[qs].w[nt * 2 + 0] = __builtin_amdgcn_perm(e1.u, e0.u, 0x07060302u);
                pf[qs].w[nt * 2 + 1] = __builtin_amdgcn_perm(e3.u, e2.u, 0x07060302u);
            }

        // sums + O^T[d][q] += V^T(stripe) . P  (MFMA cluster 2)
        __builtin_amdgcn_s_setprio(1);
#pragma unroll
        for (int qs = 0; qs < 4; qs++)
            accL[qs] = __builtin_amdgcn_mfma_f32_16x16x32_bf16(ones, pf[qs].v, accL[qs], 0, 0, 0);
#pragma unroll
        for (int qs = 0; qs < 4; qs++)
#pragma unroll
            for (int j = 0; j < 4; j++)
                of[qs][j] = __builtin_amdgcn_mfma_f32_16x16x32_bf16(vf[j], pf[qs].v, of[qs][j], 0, 0, 0);
        __builtin_amdgcn_s_setprio(0);
    }

    // ---- combine t-halves (wt=1 -> LDS overlay -> wt=0 adds) ----
    // wq=0 partials in Ks (16 KB), wq=1 partials in Vs (16 KB).
    __syncthreads();                       // all staging reads done; overlay safe
    float* cw = (wq == 0) ? (float*)&Ks[0][0] : (float*)&Vs[0][0];
    if (wt == 1) {
#pragma unroll
        for (int qs = 0; qs < 4; qs++)
#pragma unroll
            for (int j = 0; j < 4; j++)
                *(f32x4*)&cw[(qs * 4 + j) * 256 + lane * 4] = of[qs][j];
        if (lq == 0) {
#pragma unroll
            for (int qs = 0; qs < 4; qs++) accXs[(wq * 4 + qs) * 16 + lr] = accL[qs][0];
        }
    }
    __syncthreads();
    if (wt == 0) {
        float inv[4];
#pragma unroll
        for (int qs = 0; qs < 4; qs++)
            inv[qs] = 1.0f / (accL[qs][0] + accXs[(wq * 4 + qs) * 16 + lr]);
        ushort* cbp = ctx + (size_t)b * SEQ * DM;
#pragma unroll
        for (int qs = 0; qs < 4; qs++) {
            int s = s0 + qs * 16 + lr;
#pragma unroll
            for (int j = 0; j < 4; j++) {
                f32x4 o2 = of[qs][j] + *(const f32x4*)&cw[(qs * 4 + j) * 256 + lane * 4];
                ushort4 o;
                o.x = f2bf(o2[0] * inv[qs]);
                o.y = f2bf(o2[1] * inv[qs]);
                o.z = f2bf(o2[2] * inv[qs]);
                o.w = f2bf(o2[3] * inv[qs]);
                *(ushort4*)(cbp + (size_t)s * DM + hg * 64 + j * 16 + lq * 4) = o;
            }
        }
    }
}

// ---------------------------------------------------------------------------
extern "C" void kernel_launch(void* const* d_in, const int* in_sizes, int n_in,
                              void* d_out, int out_size, void* d_ws, size_t ws_size,
                              hipStream_t stream) {
    const float* x  = (const float*)d_in[0];
    const float* WQ = (const float*)d_in[1];
    const float* bQ = (const float*)d_in[2];
    const float* WK = (const float*)d_in[3];
    const float* bK = (const float*)d_in[4];
    const float* WV = (const float*)d_in[5];
    const float* bV = (const float*)d_in[6];
    const float* WO = (const float*)d_in[7];
    const float* bO = (const float*)d_in[8];

    ushort* Qb    = (ushort*)d_ws;
    ushort* Kb    = Qb + QB_ELEMS;
    ushort* Vtg   = Kb + KB_ELEMS;
    ushort* xc    = Vtg + VT_ELEMS;       // xbf (QKV input), later reused as ctx
    ushort* WqkvT = xc + XC_ELEMS;
    ushort* WoT   = WqkvT + WQKV_ELEMS;
    float*  bcat  = (float*)(WoT + WO_ELEMS);

    gqa_prep_kernel<<<641, 256, 0, stream>>>(x, WQ, WK, WV, bQ, bK, bV,
                                             xc, WqkvT, bcat);
    // QKV: 256 riders + 32x12 = 640 blocks (128x128 tiles, N=1536)
    gqa_qkv_kernel<12><<<640, 256, 0, stream>>>(
        xc, WqkvT, bcat, Qb, Kb, Vtg, WO, WoT);
    // attention: 512 blocks x 4 waves, 32 KB LDS, resource-limited 4 blk/CU
    gqa_attn_kernel<<<512, 256, 0, stream>>>(Qb, Kb, Vtg, xc);
    // O-proj: 32x16 = 512 tiles of 128x64 (2 blocks/CU, no atomics)
    gqa_oproj_kernel<<<512, 256, 0, stream>>>(xc, WoT, bO, (float*)d_out);
}

// Round 12
// 157.845 us; speedup vs baseline: 2.0502x; 1.0058x over previous
//
#include <hip/hip_runtime.h>
#include <cstdint>
#include <cstddef>

typedef short bf16x8 __attribute__((ext_vector_type(8)));
typedef float f32x4 __attribute__((ext_vector_type(4)));

#define DM 1024
#define NHEADS 16
#define NGROUPS 4
#define DK 64
#define BATCH 2
#define SEQ 2048
#define MROWS 4096

#define QB_ELEMS   ((size_t)BATCH*NHEADS*SEQ*DK)   // 4M shorts
#define KB_ELEMS   ((size_t)BATCH*NGROUPS*SEQ*DK)  // 1M
#define VT_ELEMS   KB_ELEMS                        // 1M  ([b][g][d][col] permuted)
#define XC_ELEMS   ((size_t)MROWS*DM)              // 4M  (xbf, later reused as ctx)
#define WQKV_ELEMS ((size_t)1536*DM)
#define WO_ELEMS   ((size_t)DM*DM)

#define SCL_Q 0.180336880f    // (1/sqrt(64)) * log2(e), folded into Q

__device__ __forceinline__ ushort f2bf(float f) {          // RNE
    union { float f; uint32_t u; } a; a.f = f;
    uint32_t u = a.u;
    return (ushort)((u + 0x7FFFu + ((u >> 16) & 1u)) >> 16);
}

// async global->LDS, 16B/lane; LDS dest = wave-uniform base + lane*16
__device__ __forceinline__ void gll16(const void* g, void* l) {
    __builtin_amdgcn_global_load_lds((const __attribute__((address_space(1))) void*)g,
                                     (__attribute__((address_space(3))) void*)l, 16, 0, 0);
}

// 64x64 fp32->bf16 transpose tile through LDS (tl must be float[64][65])
__device__ __forceinline__ void transpose_tile(
        const float* __restrict__ src, int src_ld, ushort* __restrict__ dst,
        int r0, int c0, int tid, float (*tl)[65])
{
    const int rr = tid >> 4, cc = (tid & 15) * 4;
#pragma unroll
    for (int p = 0; p < 4; p++) {
        int r = rr + p * 16;
        float4 v = *(const float4*)(src + (size_t)(r0 + r) * src_ld + c0 + cc);
        tl[cc + 0][r] = v.x; tl[cc + 1][r] = v.y;
        tl[cc + 2][r] = v.z; tl[cc + 3][r] = v.w;
    }
    __syncthreads();
#pragma unroll
    for (int p = 0; p < 4; p++) {
        int c = rr + p * 16;
        ushort4 o;
        o.x = f2bf(tl[c][cc + 0]); o.y = f2bf(tl[c][cc + 1]);
        o.z = f2bf(tl[c][cc + 2]); o.w = f2bf(tl[c][cc + 3]);
        *(ushort4*)(dst + (size_t)(c0 + c) * 1024 + r0 + cc) = o;
    }
}

// ---------------------------------------------------------------------------
// Prep (641 blocks): W_Q/W_K/W_V transposes -> WqkvT, x fp32->bf16, bias.
// (W_O transpose rides inside the QKV GEMM launch.)  [R9-exact]
// ---------------------------------------------------------------------------
__global__ __launch_bounds__(256) void gqa_prep_kernel(
        const float* __restrict__ x,
        const float* __restrict__ WQ, const float* __restrict__ WK,
        const float* __restrict__ WV,
        const float* __restrict__ bQ, const float* __restrict__ bK,
        const float* __restrict__ bV,
        ushort* __restrict__ xbf, ushort* __restrict__ WqkvT,
        float* __restrict__ bcat)
{
    __shared__ float tl[64][65];
    const int bid = blockIdx.x, tid = threadIdx.x;
    if (bid < 256) {            // WQ [d][c] -> WqkvT rows c
        transpose_tile(WQ, 1024, WqkvT, (bid >> 4) * 64, (bid & 15) * 64, tid, tl);
    } else if (bid < 320) {     // WK[g] [d][k] -> rows 1024+g*64
        int t = bid - 256, g = t >> 4;
        transpose_tile(WK + (size_t)g * 1024 * 64, 64,
                       WqkvT + (size_t)(1024 + g * 64) * 1024,
                       (t & 15) * 64, 0, tid, tl);
    } else if (bid < 384) {     // WV[g] -> rows 1280+g*64
        int t = bid - 320, g = t >> 4;
        transpose_tile(WV + (size_t)g * 1024 * 64, 64,
                       WqkvT + (size_t)(1280 + g * 64) * 1024,
                       (t & 15) * 64, 0, tid, tl);
    } else if (bid < 640) {     // x convert
        int cid = bid - 384;
        const float* xs = x + (size_t)cid * 16384;
        ushort* xd = xbf + (size_t)cid * 16384;
#pragma unroll
        for (int p = 0; p < 16; p++) {
            float4 v = *(const float4*)(xs + p * 1024 + tid * 4);
            ushort4 o = { f2bf(v.x), f2bf(v.y), f2bf(v.z), f2bf(v.w) };
            *(ushort4*)(xd + p * 1024 + tid * 4) = o;
        }
    } else {
        for (int i = tid; i < 1536; i += 256) {
            float v = (i < 1024) ? bQ[i] : (i < 1280 ? bK[i - 1024] : bV[i - 1280]);
            bcat[i] = v;
        }
    }
}

// ---------------------------------------------------------------------------
// QKV GEMM (R9-exact): C[4096][1536] = A*B (+bias), BT[1536][1024].
// 128x128 tile, BK=64, 4 waves (2x2, wave 64x64, acc 4x4), gll16 dbuf,
// 1 barrier/iter, 64 KB LDS, launch_bounds(256,2).
// RIDERS: first 256 blocks transpose W_O.
// ---------------------------------------------------------------------------
template<int BN>
__global__ __launch_bounds__(256, 2) void gqa_qkv_kernel(
        const ushort* __restrict__ A, const ushort* __restrict__ BT,
        const float* __restrict__ bias,
        ushort* __restrict__ Qb, ushort* __restrict__ Kb, ushort* __restrict__ Vtg,
        const float* __restrict__ WO, ushort* __restrict__ WoT)
{
    __shared__ ushort smem[4][8192];     // As buf0/1, Bs buf0/1 (64 KB)
    const int tid = threadIdx.x;
    int i = blockIdx.x;

    if (i < 256) {   // W_O transpose rider
        float (*tl)[65] = (float(*)[65])&smem[0][0];
        transpose_tile(WO, 1024, WoT, (i >> 4) * 64, (i & 15) * 64, tid, tl);
        return;
    }
    i -= 256;

    const int xcd = i & 7, slot = i >> 3;
    const int bm = (slot / BN) * 8 + xcd;
    const int bn = slot % BN;
    const int wave = tid >> 6, lane = tid & 63;
    const int wm = (wave & 1) * 64, wn = (wave >> 1) * 64;
    const int lr = lane & 15, lq = lane >> 4;
    const int swz = lr & 7;

    const ushort* srcA[4]; const ushort* srcB[4]; int dstOff[4];
#pragma unroll
    for (int p = 0; p < 4; p++) {
        int slt = p * 256 + tid;
        int row = slt >> 3, cb = (slt & 7) ^ (row & 7);
        srcA[p] = A  + (size_t)(bm * 128 + row) * 1024 + cb * 8;
        srcB[p] = BT + (size_t)(bn * 128 + row) * 1024 + cb * 8;
        dstOff[p] = p * 2048 + wave * 512;
    }

    f32x4 acc[4][4];
#pragma unroll
    for (int ii = 0; ii < 4; ii++)
#pragma unroll
        for (int j = 0; j < 4; j++) acc[ii][j] = (f32x4){0.f, 0.f, 0.f, 0.f};

#pragma unroll
    for (int p = 0; p < 4; p++) {
        gll16(srcA[p], &smem[0][dstOff[p]]);
        gll16(srcB[p], &smem[2][dstOff[p]]);
    }

    for (int kt = 0; kt < 16; kt++) {
        __syncthreads();
        if (kt < 15) {
            int buf = (kt + 1) & 1, ko = (kt + 1) * 64;
#pragma unroll
            for (int p = 0; p < 4; p++) {
                gll16(srcA[p] + ko, &smem[buf][dstOff[p]]);
                gll16(srcB[p] + ko, &smem[2 + buf][dstOff[p]]);
            }
        }
        const ushort* as = smem[kt & 1];
        const ushort* bs = smem[2 + (kt & 1)];
        bf16x8 af[2][4], bfr[2][4];
#pragma unroll
        for (int kh = 0; kh < 2; kh++) {
#pragma unroll
            for (int ii = 0; ii < 4; ii++)
                af[kh][ii] = *(const bf16x8*)&as[(wm + ii * 16 + lr) * 64 + ((kh * 4 + lq) ^ swz) * 8];
#pragma unroll
            for (int j = 0; j < 4; j++)
                bfr[kh][j] = *(const bf16x8*)&bs[(wn + j * 16 + lr) * 64 + ((kh * 4 + lq) ^ swz) * 8];
        }
#pragma unroll
        for (int kh = 0; kh < 2; kh++)
#pragma unroll
            for (int ii = 0; ii < 4; ii++)
#pragma unroll
                for (int j = 0; j < 4; j++)
                    acc[ii][j] = __builtin_amdgcn_mfma_f32_16x16x32_bf16(af[kh][ii], bfr[kh][j], acc[ii][j], 0, 0, 0);
    }

#pragma unroll
    for (int ii = 0; ii < 4; ii++) {
        int mg = bm * 128 + wm + ii * 16 + lq * 4;
        int b = mg >> 11, s = mg & 2047;
#pragma unroll
        for (int j = 0; j < 4; j++) {
            int cg = bn * 128 + wn + j * 16 + lr;
            float bv = bias[cg];
            int d = cg & 63;
            if (cg < 1024) {
                int h = cg >> 6;
                ushort* dst = Qb + ((size_t)(b * NHEADS + h) * SEQ + s) * DK + d;
#pragma unroll
                for (int r = 0; r < 4; r++)
                    dst[r * DK] = f2bf((acc[ii][j][r] + bv) * SCL_Q);
            } else if (cg < 1280) {
                int g = (cg - 1024) >> 6;
                ushort* dst = Kb + ((size_t)(b * NGROUPS + g) * SEQ + s) * DK + d;
#pragma unroll
                for (int r = 0; r < 4; r++) dst[r * DK] = f2bf(acc[ii][j][r] + bv);
            } else {
                int g = (cg - 1280) >> 6;
                // permuted V^T column: 4-key group kg -> position (kg&3)*2+(kg>>2)
                int s4 = s >> 2, kg = s4 & 7;
                int col = ((s4 >> 3) << 5) + (((((kg & 3) << 1) | (kg >> 2))) << 2);
                ushort4 pk;
                pk.x = f2bf(acc[ii][j][0] + bv); pk.y = f2bf(acc[ii][j][1] + bv);
                pk.z = f2bf(acc[ii][j][2] + bv); pk.w = f2bf(acc[ii][j][3] + bv);
                *(ushort4*)(Vtg + ((size_t)(b * NGROUPS + g) * DK + d) * SEQ + col) = pk;
            }
        }
    }
}

// ---------------------------------------------------------------------------
// O-proj GEMM (R9-exact, NJ=2): C[4096][1024] = ctx*WoT + bO.
// Tile 128x64, BK=64, 4 waves (2x2, wave 64x32, acc 4x2), gll16 dbuf,
// 1 barrier/iter, 48 KB LDS -> 512 blocks at 2/CU, no atomics.
// ---------------------------------------------------------------------------
__global__ __launch_bounds__(256, 2) void gqa_oproj_kernel(
        const ushort* __restrict__ A, const ushort* __restrict__ BT,
        const float* __restrict__ bias, float* __restrict__ outF)
{
    constexpr int NJ = 2;
    constexpr int BNT = NJ * 32;                 // tile width 64
    __shared__ ushort smem[16384 + NJ * 4096];   // As dbuf + Bs dbuf (48 KB)
    ushort* As = smem;                           // 2 bufs x 8192 ushorts
    ushort* Bs = smem + 16384;                   // 2 bufs x NJ*2048 ushorts

    const int tid = threadIdx.x;
    const int i = blockIdx.x;
    const int xcd = i & 7, slot = i >> 3;        // slot 0..63
    const int bm = (slot >> 4) * 8 + xcd;        // 0..31
    const int bn = slot & 15;                    // 0..15
    const int wave = tid >> 6, lane = tid & 63;
    const int wm = (wave & 1) * 64, wn = (wave >> 1) * (NJ * 16);
    const int lr = lane & 15, lq = lane >> 4;
    const int swz = lr & 7;

    const ushort* srcA[4]; int dstOffA[4];
    const ushort* srcB[NJ]; int dstOffB[NJ];
#pragma unroll
    for (int p = 0; p < 4; p++) {
        int slt = p * 256 + tid;
        int row = slt >> 3, cb = (slt & 7) ^ (row & 7);
        srcA[p] = A + (size_t)(bm * 128 + row) * 1024 + cb * 8;
        dstOffA[p] = p * 2048 + wave * 512;
    }
#pragma unroll
    for (int p = 0; p < NJ; p++) {
        int slt = p * 256 + tid;
        int row = slt >> 3, cb = (slt & 7) ^ (row & 7);
        srcB[p] = BT + (size_t)(bn * BNT + row) * 1024 + cb * 8;
        dstOffB[p] = p * 2048 + wave * 512;
    }

    f32x4 acc[4][NJ];
#pragma unroll
    for (int ii = 0; ii < 4; ii++)
#pragma unroll
        for (int j = 0; j < NJ; j++) acc[ii][j] = (f32x4){0.f, 0.f, 0.f, 0.f};

#pragma unroll
    for (int p = 0; p < 4; p++) gll16(srcA[p], &As[dstOffA[p]]);
#pragma unroll
    for (int p = 0; p < NJ; p++) gll16(srcB[p], &Bs[dstOffB[p]]);

    for (int kt = 0; kt < 16; kt++) {
        __syncthreads();
        if (kt < 15) {
            int buf = (kt + 1) & 1, ko = (kt + 1) * 64;
#pragma unroll
            for (int p = 0; p < 4; p++)
                gll16(srcA[p] + ko, &As[buf * 8192 + dstOffA[p]]);
#pragma unroll
            for (int p = 0; p < NJ; p++)
                gll16(srcB[p] + ko, &Bs[buf * (NJ * 2048) + dstOffB[p]]);
        }
        const ushort* as = As + (kt & 1) * 8192;
        const ushort* bs = Bs + (kt & 1) * (NJ * 2048);
        bf16x8 af[2][4], bfr[2][NJ];
#pragma unroll
        for (int kh = 0; kh < 2; kh++) {
#pragma unroll
            for (int ii = 0; ii < 4; ii++)
                af[kh][ii] = *(const bf16x8*)&as[(wm + ii * 16 + lr) * 64 + ((kh * 4 + lq) ^ swz) * 8];
#pragma unroll
            for (int j = 0; j < NJ; j++)
                bfr[kh][j] = *(const bf16x8*)&bs[(wn + j * 16 + lr) * 64 + ((kh * 4 + lq) ^ swz) * 8];
        }
#pragma unroll
        for (int kh = 0; kh < 2; kh++)
#pragma unroll
            for (int ii = 0; ii < 4; ii++)
#pragma unroll
                for (int j = 0; j < NJ; j++)
                    acc[ii][j] = __builtin_amdgcn_mfma_f32_16x16x32_bf16(af[kh][ii], bfr[kh][j], acc[ii][j], 0, 0, 0);
    }

#pragma unroll
    for (int ii = 0; ii < 4; ii++) {
        int mg = bm * 128 + wm + ii * 16 + lq * 4;
#pragma unroll
        for (int j = 0; j < NJ; j++) {
            int cg = bn * BNT + wn + j * 16 + lr;
            float bv = bias[cg];
#pragma unroll
            for (int r = 0; r < 4; r++)
                outF[(size_t)(mg + r) * DM + cg] = acc[ii][j][r] + bv;
        }
    }
}

// ---------------------------------------------------------------------------
// Attention (R12 = R9 body + qs-pipelined schedule): 512 blocks, XCD-local.
// Block = 128 q x full key sweep in 128-key tiles (16 iters). 4 waves 2x2.
// gll16 dbuf LDS 64 KB, 2 blocks/CU. Single change vs R9: the four
// independent qs-streams are software-pipelined
//   S(0);S(1);E(0);P(0);S(2);E(1);P(1);S(3);E(2);P(2);E(3);P(3)
// so each exp2/pack (trans/VALU) sits between queued MFMA clusters of a
// DIFFERENT qs -> scheduler can co-issue trans with MFMA (R9: MfmaUtil 34
// = VALUBusy 34, pipes running back-to-back serial). Named per-qs arrays
// keep all indexing compile-time (no scratch). Semantics identical.
// ---------------------------------------------------------------------------
__global__ __launch_bounds__(256, 2) void gqa_attn_kernel(
        const ushort* __restrict__ Qb, const ushort* __restrict__ Kb,
        const ushort* __restrict__ Vtg, ushort* __restrict__ ctx)
{
    __shared__ ushort Ks[2][128 * 64];   // 32 KB
    __shared__ ushort Vs[2][64 * 128];   // 32 KB

    const int tid = threadIdx.x, wave = tid >> 6, lane = tid & 63;
    const int lr = lane & 15, lq = lane >> 4;
    const int swz = lr & 7;
    const int wq = wave & 1, wt = wave >> 1;
    const int i = blockIdx.x;
    const int bg = i & 7, s2 = i >> 3;
    const int qt = s2 & 15, h = s2 >> 4;
    const int b = bg >> 2, g = bg & 3, hg = g * 4 + h;

    const ushort* Qh = Qb  + (size_t)(b * NHEADS  + hg) * SEQ * DK;
    const ushort* Kg = Kb  + (size_t)(b * NGROUPS + g)  * SEQ * DK;
    const ushort* Vg = Vtg + (size_t)(b * NGROUPS + g)  * DK * SEQ;

    const int s0 = qt * 128 + wq * 64;
    const int tb = wt * 64;              // wave's t-stripe base within tile

    bf16x8 qf[4][2];
#pragma unroll
    for (int qs = 0; qs < 4; qs++)
#pragma unroll
        for (int kh = 0; kh < 2; kh++)
            qf[qs][kh] = *(const bf16x8*)(Qh + (size_t)(s0 + qs * 16 + lr) * DK + kh * 32 + lq * 8);

    // staging: K 4 slots (row = slot>>3 in 0..127, 8 chunks/row);
    //          V 4 slots (row = slot>>4 in 0..63, 16 chunks/row, XOR low-3)
    const ushort* srcK[4]; const ushort* srcV[4]; int dstOff[4];
#pragma unroll
    for (int p = 0; p < 4; p++) {
        int slt = p * 256 + tid;
        int krow = slt >> 3, kcb = (slt & 7) ^ (krow & 7);
        srcK[p] = Kg + (size_t)krow * DK + kcb * 8;
        int vrow = slt >> 4, vc = slt & 15;
        int vcb = (vc & 8) | ((vc ^ vrow) & 7);
        srcV[p] = Vg + (size_t)vrow * SEQ + vcb * 8;
        dstOff[p] = (p * 256 + wave * 64) * 8;   // ushort offset; lane*8 added by HW
    }

    f32x4 of[4][4];
#pragma unroll
    for (int qs = 0; qs < 4; qs++)
#pragma unroll
        for (int j = 0; j < 4; j++) of[qs][j] = (f32x4){0.f, 0.f, 0.f, 0.f};
    f32x4 accL[4];
#pragma unroll
    for (int qs = 0; qs < 4; qs++) accL[qs] = (f32x4){0.f, 0.f, 0.f, 0.f};

    bf16x8 ones;
#pragma unroll
    for (int k = 0; k < 8; k++) ones[k] = (short)0x3F80;

#pragma unroll
    for (int p = 0; p < 4; p++) {
        gll16(srcK[p], &Ks[0][dstOff[p]]);
        gll16(srcV[p], &Vs[0][dstOff[p]]);
    }

    union PF { bf16x8 v; uint32_t w[4]; };

    for (int it = 0; it < 16; it++) {
        __syncthreads();
        if (it < 15) {
            int buf = (it + 1) & 1, t0 = (it + 1) * 128;
#pragma unroll
            for (int p = 0; p < 4; p++) {
                gll16(srcK[p] + (size_t)t0 * DK, &Ks[buf][dstOff[p]]);
                gll16(srcV[p] + t0, &Vs[buf][dstOff[p]]);
            }
        }
        const ushort* ks = Ks[it & 1];
        const ushort* vs = Vs[it & 1];

        bf16x8 kf[4][2];
#pragma unroll
        for (int nt = 0; nt < 4; nt++)
#pragma unroll
            for (int kh = 0; kh < 2; kh++)
                kf[nt][kh] = *(const bf16x8*)&ks[(tb + nt * 16 + lr) * 64 + ((kh * 4 + lq) ^ swz) * 8];

        bf16x8 vf[4][2];
#pragma unroll
        for (int j = 0; j < 4; j++)
#pragma unroll
            for (int kk = 0; kk < 2; kk++)
                vf[j][kk] = *(const bf16x8*)&vs[(j * 16 + lr) * 128 + (wt * 8 + ((kk * 4 + lq) ^ swz)) * 8];

        // Per-qs streams, software-pipelined (indices all compile-time):
        f32x4 sc0[4], sc1[4], sc2[4], sc3[4];
        PF pf0[2], pf1[2], pf2[2], pf3[2];

#define S_STEP(QS, SC) { \
    _Pragma("unroll") \
    for (int nt = 0; nt < 4; nt++) { \
        f32x4 s = (f32x4){0.f, 0.f, 0.f, 0.f}; \
        s = __builtin_amdgcn_mfma_f32_16x16x32_bf16(kf[nt][0], qf[QS][0], s, 0, 0, 0); \
        s = __builtin_amdgcn_mfma_f32_16x16x32_bf16(kf[nt][1], qf[QS][1], s, 0, 0, 0); \
        SC[nt] = s; } }

#define E_STEP(SC, PF_) { \
    _Pragma("unroll") \
    for (int nt = 0; nt < 4; nt++) { \
        union { float f; uint32_t u; } e0, e1, e2, e3; \
        e0.f = __builtin_amdgcn_exp2f(SC[nt][0]); \
        e1.f = __builtin_amdgcn_exp2f(SC[nt][1]); \
        e2.f = __builtin_amdgcn_exp2f(SC[nt][2]); \
        e3.f = __builtin_amdgcn_exp2f(SC[nt][3]); \
        PF_[nt >> 1].w[(nt & 1) * 2 + 0] = __builtin_amdgcn_perm(e1.u, e0.u, 0x07060302u); \
        PF_[nt >> 1].w[(nt & 1) * 2 + 1] = __builtin_amdgcn_perm(e3.u, e2.u, 0x07060302u); } }

#define P_STEP(QS, PF_) { \
    accL[QS] = __builtin_amdgcn_mfma_f32_16x16x32_bf16(ones, PF_[0].v, accL[QS], 0, 0, 0); \
    accL[QS] = __builtin_amdgcn_mfma_f32_16x16x32_bf16(ones, PF_[1].v, accL[QS], 0, 0, 0); \
    _Pragma("unroll") \
    for (int j = 0; j < 4; j++) { \
        of[QS][j] = __builtin_amdgcn_mfma_f32_16x16x32_bf16(vf[j][0], PF_[0].v, of[QS][j], 0, 0, 0); \
        of[QS][j] = __builtin_amdgcn_mfma_f32_16x16x32_bf16(vf[j][1], PF_[1].v, of[QS][j], 0, 0, 0); } }

        S_STEP(0, sc0)
        S_STEP(1, sc1)
        E_STEP(sc0, pf0)
        P_STEP(0, pf0)
        S_STEP(2, sc2)
        E_STEP(sc1, pf1)
        P_STEP(1, pf1)
        S_STEP(3, sc3)
        E_STEP(sc2, pf2)
        P_STEP(2, pf2)
        E_STEP(sc3, pf3)
        P_STEP(3, pf3)

#undef S_STEP
#undef E_STEP
#undef P_STEP
    }

    // ---- combine t-halves (wt=1 -> LDS overlay -> wt=0 adds) ----
    __syncthreads();                       // all staging reads done; overlay safe
    float* comb = (float*)&Ks[0][0];       // 32 KB: [wq][(qs*4+j)*256 + lane*4]
    float* accX = (float*)&Vs[0][0];       // [ (wq*4+qs)*16 + lr ]
    if (wt == 1) {
        float* cw = comb + wq * 4096;
#pragma unroll
        for (int qs = 0; qs < 4; qs++)
#pragma unroll
            for (int j = 0; j < 4; j++)
                *(f32x4*)&cw[(qs * 4 + j) * 256 + lane * 4] = of[qs][j];
        if (lq == 0) {
#pragma unroll
            for (int qs = 0; qs < 4; qs++) accX[(wq * 4 + qs) * 16 + lr] = accL[qs][0];
        }
    }
    __syncthreads();
    if (wt == 0) {
        const float* cw = comb + wq * 4096;
        float inv[4];
#pragma unroll
        for (int qs = 0; qs < 4; qs++)
            inv[qs] = 1.0f / (accL[qs][0] + accX[(wq * 4 + qs) * 16 + lr]);
        ushort* cbp = ctx + (size_t)b * SEQ * DM;
#pragma unroll
        for (int qs = 0; qs < 4; qs++) {
            int s = s0 + qs * 16 + lr;
#pragma unroll
            for (int j = 0; j < 4; j++) {
                f32x4 o2 = of[qs][j] + *(const f32x4*)&cw[(qs * 4 + j) * 256 + lane * 4];
                ushort4 o;
                o.x = f2bf(o2[0] * inv[qs]);
                o.y = f2bf(o2[1] * inv[qs]);
                o.z = f2bf(o2[2] * inv[qs]);
                o.w = f2bf(o2[3] * inv[qs]);
                *(ushort4*)(cbp + (size_t)s * DM + hg * 64 + j * 16 + lq * 4) = o;
            }
        }
    }
}

// ---------------------------------------------------------------------------
extern "C" void kernel_launch(void* const* d_in, const int* in_sizes, int n_in,
                              void* d_out, int out_size, void* d_ws, size_t ws_size,
                              hipStream_t stream) {
    const float* x  = (const float*)d_in[0];
    const float* WQ = (const float*)d_in[1];
    const float* bQ = (const float*)d_in[2];
    const float* WK = (const float*)d_in[3];
    const float* bK = (const float*)d_in[4];
    const float* WV = (const float*)d_in[5];
    const float* bV = (const float*)d_in[6];
    const float* WO = (const float*)d_in[7];
    const float* bO = (const float*)d_in[8];

    ushort* Qb    = (ushort*)d_ws;
    ushort* Kb    = Qb + QB_ELEMS;
    ushort* Vtg   = Kb + KB_ELEMS;
    ushort* xc    = Vtg + VT_ELEMS;       // xbf (QKV input), later reused as ctx
    ushort* WqkvT = xc + XC_ELEMS;
    ushort* WoT   = WqkvT + WQKV_ELEMS;
    float*  bcat  = (float*)(WoT + WO_ELEMS);

    gqa_prep_kernel<<<641, 256, 0, stream>>>(x, WQ, WK, WV, bQ, bK, bV,
                                             xc, WqkvT, bcat);
    // QKV: 256 riders + 32x12 = 640 blocks (128x128 tiles, N=1536)
    gqa_qkv_kernel<12><<<640, 256, 0, stream>>>(
        xc, WqkvT, bcat, Qb, Kb, Vtg, WO, WoT);
    gqa_attn_kernel<<<512, 256, 0, stream>>>(Qb, Kb, Vtg, xc);
    // O-proj: 32x16 = 512 tiles of 128x64 (2 blocks/CU, no atomics)
    gqa_oproj_kernel<<<512, 256, 0, stream>>>(xc, WoT, bO, (float*)d_out);
}